// Round 4
// baseline (408.451 us; speedup 1.0000x reference)
//
#include <hip/hip_runtime.h>
#include <math.h>

#define NODES 50000
#define NEDGE 800000
#define ETOT  (NEDGE + NODES)
#define NEGF  -1e30f   // finite -inf sentinel

// ---- GEMM1 + fused alpha epilogue: H[n,128] = X @ W; as_/ad_ = H·a_src/a_dst --
template<int ROWS>
__global__ void gemm_xw_alpha(const float* __restrict__ X, const float* __restrict__ W,
                              const float* __restrict__ a_src, const float* __restrict__ a_dst,
                              float* __restrict__ Hout, float* __restrict__ as_,
                              float* __restrict__ ad_, int n) {
    __shared__ float xs[ROWS][128];
    __shared__ float reds[2][ROWS], redd[2][ROWS];
    const int t = threadIdx.x;           // 0..127
    const int lane = t & 63, wv = t >> 6;
    const int row0 = blockIdx.x * ROWS;
    #pragma unroll
    for (int r = 0; r < ROWS; ++r) {
        int row = row0 + r;
        xs[r][t] = (row < n) ? X[(size_t)row * 128 + t] : 0.f;
    }
    __syncthreads();
    float acc[ROWS];
    #pragma unroll
    for (int r = 0; r < ROWS; ++r) acc[r] = 0.f;
    for (int k = 0; k < 128; ++k) {
        float w = W[k * 128 + t];
        #pragma unroll
        for (int r = 0; r < ROWS; ++r) acc[r] += xs[r][k] * w;
    }
    const float asv = a_src[t], adv = a_dst[t];
    #pragma unroll
    for (int r = 0; r < ROWS; ++r) {
        int row = row0 + r;
        if (row < n) Hout[(size_t)row * 128 + t] = acc[r];
        float ps = acc[r] * asv, pd = acc[r] * adv;
        #pragma unroll
        for (int off = 32; off; off >>= 1) {
            ps += __shfl_down(ps, off);
            pd += __shfl_down(pd, off);
        }
        if (lane == 0) { reds[wv][r] = ps; redd[wv][r] = pd; }
    }
    __syncthreads();
    if (t < ROWS) {
        int row = row0 + t;
        if (row < n) {
            as_[row] = reds[0][t] + reds[1][t];
            ad_[row] = redd[0][t] + redd[1][t];
        }
    }
}

// ---- GEMM2 + fused alpha: H2[n,16] = Hin @ W2; 16 lanes per node ----
__global__ void gemm_hw2_alpha(const float* __restrict__ Hin, const float* __restrict__ W,
                               const float* __restrict__ a_src, const float* __restrict__ a_dst,
                               float* __restrict__ Hout, float* __restrict__ as_,
                               float* __restrict__ ad_, int n) {
    int tid = blockIdx.x * blockDim.x + threadIdx.x;
    int node = tid >> 4, col = tid & 15;
    if (node >= n) return;
    const float* hr = Hin + (size_t)node * 128;
    float acc = 0.f;
    #pragma unroll
    for (int k = 0; k < 128; ++k) acc += hr[k] * W[k * 16 + col];
    Hout[(size_t)node * 16 + col] = acc;
    float ps = acc * a_src[col], pd = acc * a_dst[col];
    #pragma unroll
    for (int off = 1; off < 16; off <<= 1) {
        ps += __shfl_xor(ps, off);
        pd += __shfl_xor(pd, off);
    }
    if (col == 0) { as_[node] = ps; ad_[node] = pd; }
}

// =================== CSR build ====================
__global__ void csr_hist(const int* __restrict__ ei, int* __restrict__ deg) {
    int e = blockIdx.x * blockDim.x + threadIdx.x;
    if (e >= ETOT) return;
    int d = (e < NEDGE) ? ei[NEDGE + e] : e - NEDGE;
    atomicAdd(&deg[d], 1);
}

// single-block exclusive scan of deg[NODES] -> rowptr, cursor
__global__ void scan_all(const int* __restrict__ deg, int* __restrict__ rowptr,
                         int* __restrict__ cursor) {
    const int T = 1024;
    const int CH = (NODES + T - 1) / T;   // 49
    int t = threadIdx.x;
    int base = t * CH;
    int s = 0;
    for (int j = 0; j < CH; ++j) { int i = base + j; if (i < NODES) s += deg[i]; }
    int lane = t & 63, wv = t >> 6;
    int sv = s;
    #pragma unroll
    for (int off = 1; off < 64; off <<= 1) {
        int o = __shfl_up(sv, off);
        if (lane >= off) sv += o;
    }
    __shared__ int ws[16];
    if (lane == 63) ws[wv] = sv;
    __syncthreads();
    int add = 0;
    for (int j = 0; j < wv; ++j) add += ws[j];
    int run = add + sv - s;               // exclusive prefix for this thread's chunk
    for (int j = 0; j < CH; ++j) {
        int i = base + j;
        if (i < NODES) { rowptr[i] = run; cursor[i] = run; run += deg[i]; }
    }
    if (t == T - 1) rowptr[NODES] = run;  // == ETOT
}

__global__ void csr_fill(const int* __restrict__ ei, int* __restrict__ cursor,
                         int* __restrict__ srcs) {
    int e = blockIdx.x * blockDim.x + threadIdx.x;
    if (e >= ETOT) return;
    int s, d;
    if (e < NEDGE) { s = ei[e]; d = ei[NEDGE + e]; }
    else           { s = d = e - NEDGE; }
    int pos = atomicAdd(&cursor[d], 1);
    srcs[pos] = s;
}

// ---- per-node edge softmax: w_e = exp(v_e - m), inv_den = 1/(sum w + eps) ----
// one wave per node, lanes strided over the node's edges
__global__ void edge_softmax(const int* __restrict__ rowptr, const int* __restrict__ srcs,
                             const float* __restrict__ as_, const float* __restrict__ ad_,
                             float* __restrict__ exw, float* __restrict__ inv_den) {
    int wid = (blockIdx.x * blockDim.x + threadIdx.x) >> 6;
    int lane = threadIdx.x & 63;
    if (wid >= NODES) return;
    const int beg = rowptr[wid], end = rowptr[wid + 1];
    const float adv = ad_[wid];
    float m = NEGF;
    for (int i = beg + lane; i < end; i += 64) {
        float v = as_[srcs[i]] + adv;
        v = (v >= 0.f) ? v : 0.2f * v;
        exw[i] = v;
        m = fmaxf(m, v);
    }
    #pragma unroll
    for (int off = 32; off; off >>= 1) m = fmaxf(m, __shfl_xor(m, off));
    float s = 0.f;
    for (int i = beg + lane; i < end; i += 64) {
        float w = __expf(exw[i] - m);
        exw[i] = w;
        s += w;
    }
    #pragma unroll
    for (int off = 32; off; off >>= 1) s += __shfl_xor(s, off);
    if (lane == 0) inv_den[wid] = 1.f / (s + 1e-16f);
}

// ---- layer 1 aggregate: pure weighted gather + bias + ReLU (F=128) ----
__global__ void gat_aggregate128(const int* __restrict__ rowptr, const int* __restrict__ srcs,
                                 const float* __restrict__ exw, const float* __restrict__ inv_den,
                                 const float* __restrict__ H, const float* __restrict__ b,
                                 float* __restrict__ out) {
    int wid = (blockIdx.x * blockDim.x + threadIdx.x) >> 6;
    int lane = threadIdx.x & 63;
    if (wid >= NODES) return;
    const int beg = rowptr[wid], end = rowptr[wid + 1];
    float ax = 0.f, ay = 0.f;
    int i = beg;
    for (; i + 4 <= end; i += 4) {
        int s0 = srcs[i], s1 = srcs[i + 1], s2 = srcs[i + 2], s3 = srcs[i + 3];
        float w0 = exw[i], w1 = exw[i + 1], w2 = exw[i + 2], w3 = exw[i + 3];
        const float2 h0 = *(const float2*)(H + (size_t)s0 * 128 + lane * 2);
        const float2 h1 = *(const float2*)(H + (size_t)s1 * 128 + lane * 2);
        const float2 h2 = *(const float2*)(H + (size_t)s2 * 128 + lane * 2);
        const float2 h3 = *(const float2*)(H + (size_t)s3 * 128 + lane * 2);
        ax += w0 * h0.x + w1 * h1.x + w2 * h2.x + w3 * h3.x;
        ay += w0 * h0.y + w1 * h1.y + w2 * h2.y + w3 * h3.y;
    }
    for (; i < end; ++i) {
        int s0 = srcs[i];
        float w0 = exw[i];
        const float2 h0 = *(const float2*)(H + (size_t)s0 * 128 + lane * 2);
        ax += w0 * h0.x;
        ay += w0 * h0.y;
    }
    float invd = inv_den[wid];
    float2 o;
    o.x = fmaxf(ax * invd + b[lane * 2], 0.f);
    o.y = fmaxf(ay * invd + b[lane * 2 + 1], 0.f);
    *(float2*)(out + (size_t)wid * 128 + lane * 2) = o;
}

// ---- layer 2 aggregate (F=16, 4 edge-slots/wave) + bias + log_softmax ----
__global__ void gat_aggregate16_lsm(const int* __restrict__ rowptr, const int* __restrict__ srcs,
                                    const float* __restrict__ exw, const float* __restrict__ inv_den,
                                    const float* __restrict__ H, const float* __restrict__ b,
                                    float* __restrict__ out) {
    int wid = (blockIdx.x * blockDim.x + threadIdx.x) >> 6;
    int lane = threadIdx.x & 63;
    int slot = lane >> 4, k = lane & 15;
    if (wid >= NODES) return;
    const int beg = rowptr[wid], end = rowptr[wid + 1];
    float acc = 0.f;
    for (int i = beg + slot; i < end; i += 4) {
        int s = srcs[i];
        acc += exw[i] * H[(size_t)s * 16 + k];
    }
    // combine the 4 slots (plain sums now — weights already exponentiated)
    acc += __shfl_xor(acc, 16);
    acc += __shfl_xor(acc, 32);
    float v = acc * inv_den[wid] + b[k];
    // log_softmax across the 16 features
    float mx = v;
    #pragma unroll
    for (int off = 1; off < 16; off <<= 1) mx = fmaxf(mx, __shfl_xor(mx, off));
    float ex = __expf(v - mx), ssum = ex;
    #pragma unroll
    for (int off = 1; off < 16; off <<= 1) ssum += __shfl_xor(ssum, off);
    float r = v - mx - __logf(ssum);
    if (lane < 16) out[(size_t)wid * 16 + k] = r;
}

extern "C" void kernel_launch(void* const* d_in, const int* in_sizes, int n_in,
                              void* d_out, int out_size, void* d_ws, size_t ws_size,
                              hipStream_t stream) {
    const float* x      = (const float*)d_in[0];
    const int*   ei     = (const int*)d_in[1];   // [2, E] int32 on device
    const float* W1     = (const float*)d_in[2];
    const float* a_src1 = (const float*)d_in[3];
    const float* a_dst1 = (const float*)d_in[4];
    const float* b1     = (const float*)d_in[5];
    const float* W2     = (const float*)d_in[6];
    const float* a_src2 = (const float*)d_in[7];
    const float* a_dst2 = (const float*)d_in[8];
    const float* b2     = (const float*)d_in[9];
    float* out = (float*)d_out;

    // ---- workspace layout ----
    float* p = (float*)d_ws;
    float* h1      = p; p += (size_t)NODES * 128;   // 25.6 MB
    float* agg1    = p; p += (size_t)NODES * 128;   // 25.6 MB
    float* h2      = p; p += (size_t)NODES * 16;    //  3.2 MB
    float* as_     = p; p += NODES;
    float* ad_     = p; p += NODES;
    float* inv_den = p; p += NODES;
    float* exw     = p; p += ETOT;
    int* ip = (int*)p;
    int* deg    = ip; ip += NODES;
    int* cursor = ip; ip += NODES;
    int* rowptr = ip; ip += NODES + 1;
    int* srcs   = ip; ip += ETOT;

    const int EB = (ETOT + 255) / 256;
    const int WAVEGRID = (NODES * 64 + 255) / 256;

    // ---- CSR build (shared by both layers) ----
    hipMemsetAsync(deg, 0, NODES * sizeof(int), stream);
    csr_hist<<<EB, 256, 0, stream>>>(ei, deg);
    scan_all<<<1, 1024, 0, stream>>>(deg, rowptr, cursor);
    csr_fill<<<EB, 256, 0, stream>>>(ei, cursor, srcs);

    // ---- layer 1 ----
    gemm_xw_alpha<8><<<(NODES + 7) / 8, 128, 0, stream>>>(x, W1, a_src1, a_dst1, h1, as_, ad_, NODES);
    edge_softmax<<<WAVEGRID, 256, 0, stream>>>(rowptr, srcs, as_, ad_, exw, inv_den);
    gat_aggregate128<<<WAVEGRID, 256, 0, stream>>>(rowptr, srcs, exw, inv_den, h1, b1, agg1);

    // ---- layer 2 ----
    gemm_hw2_alpha<<<(NODES * 16 + 255) / 256, 256, 0, stream>>>(agg1, W2, a_src2, a_dst2, h2, as_, ad_, NODES);
    edge_softmax<<<WAVEGRID, 256, 0, stream>>>(rowptr, srcs, as_, ad_, exw, inv_den);
    gat_aggregate16_lsm<<<WAVEGRID, 256, 0, stream>>>(rowptr, srcs, exw, inv_den, h2, b2, out);
}

// Round 5
// 263.756 us; speedup vs baseline: 1.5486x; 1.5486x over previous
//
#include <hip/hip_runtime.h>
#include <math.h>

#define NODES 50000
#define NEDGE 800000
#define ETOT  (NEDGE + NODES)
#define NEGF  -1e30f   // finite -inf sentinel
#define CAP   96       // per-wave LDS edge cache (max degree ~45 for this graph)

// ---- GEMM1 + fused alpha epilogue: H[n,128] = X @ W; as_/ad_ = H·a_src/a_dst --
template<int ROWS>
__global__ void gemm_xw_alpha(const float* __restrict__ X, const float* __restrict__ W,
                              const float* __restrict__ a_src, const float* __restrict__ a_dst,
                              float* __restrict__ Hout, float* __restrict__ as_,
                              float* __restrict__ ad_, int n) {
    __shared__ float xs[ROWS][128];
    __shared__ float reds[2][ROWS], redd[2][ROWS];
    const int t = threadIdx.x;           // 0..127
    const int lane = t & 63, wv = t >> 6;
    const int row0 = blockIdx.x * ROWS;
    #pragma unroll
    for (int r = 0; r < ROWS; ++r) {
        int row = row0 + r;
        xs[r][t] = (row < n) ? X[(size_t)row * 128 + t] : 0.f;
    }
    __syncthreads();
    float acc[ROWS];
    #pragma unroll
    for (int r = 0; r < ROWS; ++r) acc[r] = 0.f;
    for (int k = 0; k < 128; ++k) {
        float w = W[k * 128 + t];
        #pragma unroll
        for (int r = 0; r < ROWS; ++r) acc[r] += xs[r][k] * w;
    }
    const float asv = a_src[t], adv = a_dst[t];
    #pragma unroll
    for (int r = 0; r < ROWS; ++r) {
        int row = row0 + r;
        if (row < n) Hout[(size_t)row * 128 + t] = acc[r];
        float ps = acc[r] * asv, pd = acc[r] * adv;
        #pragma unroll
        for (int off = 32; off; off >>= 1) {
            ps += __shfl_down(ps, off);
            pd += __shfl_down(pd, off);
        }
        if (lane == 0) { reds[wv][r] = ps; redd[wv][r] = pd; }
    }
    __syncthreads();
    if (t < ROWS) {
        int row = row0 + t;
        if (row < n) {
            as_[row] = reds[0][t] + reds[1][t];
            ad_[row] = redd[0][t] + redd[1][t];
        }
    }
}

// ---- GEMM2 + fused alpha: H2[n,16] = Hin @ W2 (W2 staged in LDS) ----
__global__ void gemm_hw2_alpha(const float* __restrict__ Hin, const float* __restrict__ W,
                               const float* __restrict__ a_src, const float* __restrict__ a_dst,
                               float* __restrict__ Hout, float* __restrict__ as_,
                               float* __restrict__ ad_, int n) {
    __shared__ float wl[128 * 16];
    for (int i = threadIdx.x; i < 128 * 16; i += 256) wl[i] = W[i];
    __syncthreads();
    int tid = blockIdx.x * blockDim.x + threadIdx.x;
    int node = tid >> 4, col = tid & 15;
    if (node >= n) return;
    const float* hr = Hin + (size_t)node * 128;
    float acc = 0.f;
    #pragma unroll
    for (int k = 0; k < 128; ++k) acc += hr[k] * wl[k * 16 + col];
    Hout[(size_t)node * 16 + col] = acc;
    float ps = acc * a_src[col], pd = acc * a_dst[col];
    #pragma unroll
    for (int off = 1; off < 16; off <<= 1) {
        ps += __shfl_xor(ps, off);
        pd += __shfl_xor(pd, off);
    }
    if (col == 0) { as_[node] = ps; ad_[node] = pd; }
}

// =================== CSR build ====================
__global__ void csr_hist(const int* __restrict__ ei, int* __restrict__ deg) {
    int e = blockIdx.x * blockDim.x + threadIdx.x;
    if (e >= ETOT) return;
    int d = (e < NEDGE) ? ei[NEDGE + e] : e - NEDGE;
    atomicAdd(&deg[d], 1);
}

// per-256-chunk sums
__global__ void scan1(const int* __restrict__ deg, int* __restrict__ bsum) {
    int i = blockIdx.x * 256 + threadIdx.x;
    int v = (i < NODES) ? deg[i] : 0;
    #pragma unroll
    for (int off = 32; off; off >>= 1) v += __shfl_down(v, off);
    __shared__ int ws[4];
    if ((threadIdx.x & 63) == 0) ws[threadIdx.x >> 6] = v;
    __syncthreads();
    if (threadIdx.x == 0) bsum[blockIdx.x] = ws[0] + ws[1] + ws[2] + ws[3];
}

// single-block exclusive scan of nb (<=256) block sums
__global__ void scan2(int* __restrict__ bsum, int nb) {
    int t = threadIdx.x;
    int lane = t & 63, w = t >> 6;
    int v = (t < nb) ? bsum[t] : 0;
    int sv = v;
    #pragma unroll
    for (int off = 1; off < 64; off <<= 1) {
        int o = __shfl_up(sv, off);
        if (lane >= off) sv += o;
    }
    __shared__ int wsum[4];
    if (lane == 63) wsum[w] = sv;
    __syncthreads();
    int add = 0;
    for (int j = 0; j < w; ++j) add += wsum[j];
    sv += add;
    if (t < nb) bsum[t] = sv - v;   // exclusive
}

// per-chunk scan + global offset -> rowptr, cursor
__global__ void scan3(const int* __restrict__ deg, const int* __restrict__ bsum,
                      int* __restrict__ rowptr, int* __restrict__ cursor) {
    int i = blockIdx.x * 256 + threadIdx.x;
    int v = (i < NODES) ? deg[i] : 0;
    int lane = threadIdx.x & 63, w = threadIdx.x >> 6;
    int sv = v;
    #pragma unroll
    for (int off = 1; off < 64; off <<= 1) {
        int o = __shfl_up(sv, off);
        if (lane >= off) sv += o;
    }
    __shared__ int wsum[4];
    if (lane == 63) wsum[w] = sv;
    __syncthreads();
    int add = bsum[blockIdx.x];
    for (int j = 0; j < w; ++j) add += wsum[j];
    int excl = add + sv - v;
    if (i < NODES) { rowptr[i] = excl; cursor[i] = excl; }
    if (i == NODES - 1) rowptr[NODES] = excl + v;
}

__global__ void csr_fill(const int* __restrict__ ei, int* __restrict__ cursor,
                         int* __restrict__ srcs) {
    int e = blockIdx.x * blockDim.x + threadIdx.x;
    if (e >= ETOT) return;
    int s, d;
    if (e < NEDGE) { s = ei[e]; d = ei[NEDGE + e]; }
    else           { s = d = e - NEDGE; }
    int pos = atomicAdd(&cursor[d], 1);
    srcs[pos] = s;
}

// ---- layer 1: fused per-node softmax + weighted gather + bias + ReLU (F=128) --
// one wave per node; phase 1: lanes stride edges, scores+srcs cached in LDS;
// phase 2: pure weighted gather, lane covers features {2l, 2l+1}
__global__ void gat_fused128(const int* __restrict__ rowptr, const int* __restrict__ srcs,
                             const float* __restrict__ as_, const float* __restrict__ ad_,
                             const float* __restrict__ H, const float* __restrict__ b,
                             float* __restrict__ out) {
    __shared__ float sw[4][CAP];
    __shared__ int   ss[4][CAP];
    int wid = (blockIdx.x * blockDim.x + threadIdx.x) >> 6;
    int lane = threadIdx.x & 63;
    int wv = (threadIdx.x >> 6) & 3;
    if (wid >= NODES) return;
    const int beg = rowptr[wid], deg = rowptr[wid + 1] - beg;
    const float adv = ad_[wid];
    // phase 1a: scores + max
    float m = NEGF;
    for (int i = lane; i < deg; i += 64) {
        int s = srcs[beg + i];
        float v = as_[s] + adv;
        v = (v >= 0.f) ? v : 0.2f * v;
        if (i < CAP) { sw[wv][i] = v; ss[wv][i] = s; }
        m = fmaxf(m, v);
    }
    #pragma unroll
    for (int off = 32; off; off >>= 1) m = fmaxf(m, __shfl_xor(m, off));
    // phase 1b: exp + denominator
    float den = 0.f;
    for (int i = lane; i < deg; i += 64) {
        float v;
        if (i < CAP) v = sw[wv][i];
        else { int s = srcs[beg + i]; v = as_[s] + adv; v = (v >= 0.f) ? v : 0.2f * v; }
        float w = __expf(v - m);
        if (i < CAP) sw[wv][i] = w;
        den += w;
    }
    #pragma unroll
    for (int off = 32; off; off >>= 1) den += __shfl_xor(den, off);
    const float invd = 1.f / (den + 1e-16f);
    // phase 2: weighted gather (w, s broadcast from LDS)
    float ax = 0.f, ay = 0.f;
    const int nl = deg < CAP ? deg : CAP;
    int i = 0;
    for (; i + 4 <= nl; i += 4) {
        float w0 = sw[wv][i], w1 = sw[wv][i + 1], w2 = sw[wv][i + 2], w3 = sw[wv][i + 3];
        int s0 = ss[wv][i], s1 = ss[wv][i + 1], s2 = ss[wv][i + 2], s3 = ss[wv][i + 3];
        const float2 h0 = *(const float2*)(H + (size_t)s0 * 128 + lane * 2);
        const float2 h1 = *(const float2*)(H + (size_t)s1 * 128 + lane * 2);
        const float2 h2 = *(const float2*)(H + (size_t)s2 * 128 + lane * 2);
        const float2 h3 = *(const float2*)(H + (size_t)s3 * 128 + lane * 2);
        ax += w0 * h0.x + w1 * h1.x + w2 * h2.x + w3 * h3.x;
        ay += w0 * h0.y + w1 * h1.y + w2 * h2.y + w3 * h3.y;
    }
    for (; i < nl; ++i) {
        float w0 = sw[wv][i];
        int s0 = ss[wv][i];
        const float2 h0 = *(const float2*)(H + (size_t)s0 * 128 + lane * 2);
        ax += w0 * h0.x;
        ay += w0 * h0.y;
    }
    for (int j = CAP; j < deg; ++j) {   // correctness fallback, ~never taken
        int s0 = srcs[beg + j];
        float v = as_[s0] + adv; v = (v >= 0.f) ? v : 0.2f * v;
        float w0 = __expf(v - m);
        const float2 h0 = *(const float2*)(H + (size_t)s0 * 128 + lane * 2);
        ax += w0 * h0.x;
        ay += w0 * h0.y;
    }
    float2 o;
    o.x = fmaxf(ax * invd + b[lane * 2], 0.f);
    o.y = fmaxf(ay * invd + b[lane * 2 + 1], 0.f);
    *(float2*)(out + (size_t)wid * 128 + lane * 2) = o;
}

// ---- layer 2: fused softmax + aggregate (F=16, 4 slots/wave) + bias + lsm ----
__global__ void gat_fused16_lsm(const int* __restrict__ rowptr, const int* __restrict__ srcs,
                                const float* __restrict__ as_, const float* __restrict__ ad_,
                                const float* __restrict__ H, const float* __restrict__ b,
                                float* __restrict__ out) {
    __shared__ float sw[4][CAP];
    __shared__ int   ss[4][CAP];
    int wid = (blockIdx.x * blockDim.x + threadIdx.x) >> 6;
    int lane = threadIdx.x & 63;
    int wv = (threadIdx.x >> 6) & 3;
    int slot = lane >> 4, k = lane & 15;
    if (wid >= NODES) return;
    const int beg = rowptr[wid], deg = rowptr[wid + 1] - beg;
    const float adv = ad_[wid];
    float m = NEGF;
    for (int i = lane; i < deg; i += 64) {
        int s = srcs[beg + i];
        float v = as_[s] + adv;
        v = (v >= 0.f) ? v : 0.2f * v;
        if (i < CAP) { sw[wv][i] = v; ss[wv][i] = s; }
        m = fmaxf(m, v);
    }
    #pragma unroll
    for (int off = 32; off; off >>= 1) m = fmaxf(m, __shfl_xor(m, off));
    float den = 0.f;
    for (int i = lane; i < deg; i += 64) {
        float v;
        if (i < CAP) v = sw[wv][i];
        else { int s = srcs[beg + i]; v = as_[s] + adv; v = (v >= 0.f) ? v : 0.2f * v; }
        float w = __expf(v - m);
        if (i < CAP) sw[wv][i] = w;
        den += w;
    }
    #pragma unroll
    for (int off = 32; off; off >>= 1) den += __shfl_xor(den, off);
    const float invd = 1.f / (den + 1e-16f);
    // phase 2: each 16-lane slot-group takes every 4th edge
    float acc = 0.f;
    const int nl = deg < CAP ? deg : CAP;
    for (int i = slot; i < nl; i += 4) {
        acc += sw[wv][i] * H[(size_t)ss[wv][i] * 16 + k];
    }
    for (int j = CAP + slot; j < deg; j += 4) {   // fallback, ~never taken
        int s = srcs[beg + j];
        float v = as_[s] + adv; v = (v >= 0.f) ? v : 0.2f * v;
        acc += __expf(v - m) * H[(size_t)s * 16 + k];
    }
    acc += __shfl_xor(acc, 16);
    acc += __shfl_xor(acc, 32);
    float v = acc * invd + b[k];
    // log_softmax across the 16 features
    float mx = v;
    #pragma unroll
    for (int off = 1; off < 16; off <<= 1) mx = fmaxf(mx, __shfl_xor(mx, off));
    float ex = __expf(v - mx), ssum = ex;
    #pragma unroll
    for (int off = 1; off < 16; off <<= 1) ssum += __shfl_xor(ssum, off);
    float r = v - mx - __logf(ssum);
    if (lane < 16) out[(size_t)wid * 16 + k] = r;
}

extern "C" void kernel_launch(void* const* d_in, const int* in_sizes, int n_in,
                              void* d_out, int out_size, void* d_ws, size_t ws_size,
                              hipStream_t stream) {
    const float* x      = (const float*)d_in[0];
    const int*   ei     = (const int*)d_in[1];   // [2, E] int32 on device
    const float* W1     = (const float*)d_in[2];
    const float* a_src1 = (const float*)d_in[3];
    const float* a_dst1 = (const float*)d_in[4];
    const float* b1     = (const float*)d_in[5];
    const float* W2     = (const float*)d_in[6];
    const float* a_src2 = (const float*)d_in[7];
    const float* a_dst2 = (const float*)d_in[8];
    const float* b2     = (const float*)d_in[9];
    float* out = (float*)d_out;

    // ---- workspace layout ----
    float* p = (float*)d_ws;
    float* h1      = p; p += (size_t)NODES * 128;   // 25.6 MB
    float* agg1    = p; p += (size_t)NODES * 128;   // 25.6 MB
    float* h2      = p; p += (size_t)NODES * 16;    //  3.2 MB
    float* as_     = p; p += NODES;
    float* ad_     = p; p += NODES;
    int* ip = (int*)p;
    int* deg    = ip; ip += NODES;
    int* cursor = ip; ip += NODES;
    int* rowptr = ip; ip += NODES + 1;
    int* srcs   = ip; ip += ETOT;
    int* bsum   = ip; ip += 256;

    const int EB = (ETOT + 255) / 256;
    const int NB = (NODES + 255) / 256;   // 196 chunks
    const int WAVEGRID = (NODES * 64 + 255) / 256;

    // ---- CSR build (shared by both layers) ----
    hipMemsetAsync(deg, 0, NODES * sizeof(int), stream);
    csr_hist<<<EB, 256, 0, stream>>>(ei, deg);
    scan1<<<NB, 256, 0, stream>>>(deg, bsum);
    scan2<<<1, 256, 0, stream>>>(bsum, NB);
    scan3<<<NB, 256, 0, stream>>>(deg, bsum, rowptr, cursor);
    csr_fill<<<EB, 256, 0, stream>>>(ei, cursor, srcs);

    // ---- layer 1 ----
    gemm_xw_alpha<8><<<(NODES + 7) / 8, 128, 0, stream>>>(x, W1, a_src1, a_dst1, h1, as_, ad_, NODES);
    gat_fused128<<<WAVEGRID, 256, 0, stream>>>(rowptr, srcs, as_, ad_, h1, b1, agg1);

    // ---- layer 2 ----
    gemm_hw2_alpha<<<(NODES * 16 + 255) / 256, 256, 0, stream>>>(agg1, W2, a_src2, a_dst2, h2, as_, ad_, NODES);
    gat_fused16_lsm<<<WAVEGRID, 256, 0, stream>>>(rowptr, srcs, as_, ad_, h2, b2, out);
}

// Round 6
// 216.568 us; speedup vs baseline: 1.8860x; 1.2179x over previous
//
#include <hip/hip_runtime.h>
#include <math.h>

#define NODES 50000
#define NEDGE 800000
#define ETOT  (NEDGE + NODES)
#define NEGF  -1e30f   // finite -inf sentinel
#define CAP   96       // per-wave LDS edge cache (max degree ~45 for this graph)

typedef unsigned short ushort_t;
typedef unsigned int uint_t;

__device__ __forceinline__ ushort_t f2bf(float f) {   // fp32 -> bf16 RNE
    uint_t u = __float_as_uint(f);
    return (ushort_t)((u + 0x7fffu + ((u >> 16) & 1u)) >> 16);
}

// ---- GEMM1 + fused alpha: 32 rows/block, 256 thr, acc[4][4]; h1 out bf16 ----
__global__ void gemm_xw_alpha(const float* __restrict__ X, const float* __restrict__ W,
                              const float* __restrict__ a_src, const float* __restrict__ a_dst,
                              ushort_t* __restrict__ Hb, float* __restrict__ as_,
                              float* __restrict__ ad_, int n) {
    __shared__ float xs[32][129];                       // +1 pad
    const int t = threadIdx.x;                          // 0..255
    const int ct = t & 31;                              // cols: ct, ct+32, ct+64, ct+96
    const int rg = t >> 5;                              // row group 0..7 -> rows rg*4..+3
    const int row0 = blockIdx.x * 32;
    #pragma unroll
    for (int i = 0; i < 16; ++i) {
        int idx = i * 256 + t;
        int r = idx >> 7, c = idx & 127;
        int row = row0 + r;
        xs[r][c] = (row < n) ? X[(size_t)row * 128 + c] : 0.f;
    }
    __syncthreads();
    float acc[4][4];
    #pragma unroll
    for (int r = 0; r < 4; ++r)
        #pragma unroll
        for (int c = 0; c < 4; ++c) acc[r][c] = 0.f;
    for (int k = 0; k < 128; ++k) {
        float w0 = W[k * 128 + ct], w1 = W[k * 128 + ct + 32];
        float w2 = W[k * 128 + ct + 64], w3 = W[k * 128 + ct + 96];
        #pragma unroll
        for (int r = 0; r < 4; ++r) {
            float xv = xs[rg * 4 + r][k];
            acc[r][0] += xv * w0; acc[r][1] += xv * w1;
            acc[r][2] += xv * w2; acc[r][3] += xv * w3;
        }
    }
    #pragma unroll
    for (int r = 0; r < 4; ++r) {
        int row = row0 + rg * 4 + r;
        bool ok = row < n;
        float s = 0.f, d = 0.f;
        #pragma unroll
        for (int c = 0; c < 4; ++c) {
            float v = acc[r][c];
            int col = ct + 32 * c;
            if (ok) Hb[(size_t)row * 128 + col] = f2bf(v);
            s += v * a_src[col];
            d += v * a_dst[col];
        }
        #pragma unroll
        for (int off = 16; off; off >>= 1) {            // reduce across the 32-lane col group
            s += __shfl_down(s, off, 32);
            d += __shfl_down(d, off, 32);
        }
        if (ct == 0 && ok) { as_[row] = s; ad_[row] = d; }
    }
}

// ---- GEMM2 + fused alpha: H2[n,16] = Hin @ W2 (W2 staged in LDS) ----
__global__ void gemm_hw2_alpha(const float* __restrict__ Hin, const float* __restrict__ W,
                               const float* __restrict__ a_src, const float* __restrict__ a_dst,
                               float* __restrict__ Hout, float* __restrict__ as_,
                               float* __restrict__ ad_, int n) {
    __shared__ float wl[128 * 16];
    for (int i = threadIdx.x; i < 128 * 16; i += 256) wl[i] = W[i];
    __syncthreads();
    int tid = blockIdx.x * blockDim.x + threadIdx.x;
    int node = tid >> 4, col = tid & 15;
    if (node >= n) return;
    const float* hr = Hin + (size_t)node * 128;
    float acc = 0.f;
    #pragma unroll
    for (int k = 0; k < 128; ++k) acc += hr[k] * wl[k * 16 + col];
    Hout[(size_t)node * 16 + col] = acc;
    float ps = acc * a_src[col], pd = acc * a_dst[col];
    #pragma unroll
    for (int off = 1; off < 16; off <<= 1) {
        ps += __shfl_xor(ps, off);
        pd += __shfl_xor(pd, off);
    }
    if (col == 0) { as_[node] = ps; ad_[node] = pd; }
}

// =================== CSR build ====================
__global__ void csr_hist(const int* __restrict__ ei, int* __restrict__ deg) {
    int e = blockIdx.x * blockDim.x + threadIdx.x;
    if (e >= ETOT) return;
    int d = (e < NEDGE) ? ei[NEDGE + e] : e - NEDGE;
    atomicAdd(&deg[d], 1);
}

__global__ void scan1(const int* __restrict__ deg, int* __restrict__ bsum) {
    int i = blockIdx.x * 256 + threadIdx.x;
    int v = (i < NODES) ? deg[i] : 0;
    #pragma unroll
    for (int off = 32; off; off >>= 1) v += __shfl_down(v, off);
    __shared__ int ws[4];
    if ((threadIdx.x & 63) == 0) ws[threadIdx.x >> 6] = v;
    __syncthreads();
    if (threadIdx.x == 0) bsum[blockIdx.x] = ws[0] + ws[1] + ws[2] + ws[3];
}

__global__ void scan2(int* __restrict__ bsum, int nb) {
    int t = threadIdx.x;
    int lane = t & 63, w = t >> 6;
    int v = (t < nb) ? bsum[t] : 0;
    int sv = v;
    #pragma unroll
    for (int off = 1; off < 64; off <<= 1) {
        int o = __shfl_up(sv, off);
        if (lane >= off) sv += o;
    }
    __shared__ int wsum[4];
    if (lane == 63) wsum[w] = sv;
    __syncthreads();
    int add = 0;
    for (int j = 0; j < w; ++j) add += wsum[j];
    sv += add;
    if (t < nb) bsum[t] = sv - v;   // exclusive
}

__global__ void scan3(const int* __restrict__ deg, const int* __restrict__ bsum,
                      int* __restrict__ rowptr, int* __restrict__ cursor) {
    int i = blockIdx.x * 256 + threadIdx.x;
    int v = (i < NODES) ? deg[i] : 0;
    int lane = threadIdx.x & 63, w = threadIdx.x >> 6;
    int sv = v;
    #pragma unroll
    for (int off = 1; off < 64; off <<= 1) {
        int o = __shfl_up(sv, off);
        if (lane >= off) sv += o;
    }
    __shared__ int wsum[4];
    if (lane == 63) wsum[w] = sv;
    __syncthreads();
    int add = bsum[blockIdx.x];
    for (int j = 0; j < w; ++j) add += wsum[j];
    int excl = add + sv - v;
    if (i < NODES) { rowptr[i] = excl; cursor[i] = excl; }
    if (i == NODES - 1) rowptr[NODES] = excl + v;
}

__global__ void csr_fill(const int* __restrict__ ei, int* __restrict__ cursor,
                         ushort_t* __restrict__ srcs) {
    int e = blockIdx.x * blockDim.x + threadIdx.x;
    if (e >= ETOT) return;
    int s, d;
    if (e < NEDGE) { s = ei[e]; d = ei[NEDGE + e]; }
    else           { s = d = e - NEDGE; }
    int pos = atomicAdd(&cursor[d], 1);
    srcs[pos] = (ushort_t)s;
}

// ---- layer 1: fused softmax + weighted bf16 gather + bias + ReLU (F=128) ----
__global__ void gat_fused128(const int* __restrict__ rowptr, const ushort_t* __restrict__ srcs,
                             const float* __restrict__ as_, const float* __restrict__ ad_,
                             const ushort_t* __restrict__ Hb, const float* __restrict__ b,
                             float* __restrict__ out) {
    __shared__ float sw[4][CAP];
    __shared__ int   ss[4][CAP];
    int wid = (blockIdx.x * blockDim.x + threadIdx.x) >> 6;
    int lane = threadIdx.x & 63;
    int wv = (threadIdx.x >> 6) & 3;
    if (wid >= NODES) return;
    const int beg = rowptr[wid], deg = rowptr[wid + 1] - beg;
    const float adv = ad_[wid];
    float m = NEGF;
    for (int i = lane; i < deg; i += 64) {
        int s = srcs[beg + i];
        float v = as_[s] + adv;
        v = (v >= 0.f) ? v : 0.2f * v;
        if (i < CAP) { sw[wv][i] = v; ss[wv][i] = s; }
        m = fmaxf(m, v);
    }
    #pragma unroll
    for (int off = 32; off; off >>= 1) m = fmaxf(m, __shfl_xor(m, off));
    float den = 0.f;
    for (int i = lane; i < deg; i += 64) {
        float v;
        if (i < CAP) v = sw[wv][i];
        else { int s = srcs[beg + i]; v = as_[s] + adv; v = (v >= 0.f) ? v : 0.2f * v; }
        float w = __expf(v - m);
        if (i < CAP) sw[wv][i] = w;
        den += w;
    }
    #pragma unroll
    for (int off = 32; off; off >>= 1) den += __shfl_xor(den, off);
    const float invd = 1.f / (den + 1e-16f);
    // phase 2: weighted gather of bf16 rows; lane covers features {2l, 2l+1}
    float ax = 0.f, ay = 0.f;
    const int nl = deg < CAP ? deg : CAP;
    int i = 0;
    for (; i + 4 <= nl; i += 4) {
        float w0 = sw[wv][i], w1 = sw[wv][i + 1], w2 = sw[wv][i + 2], w3 = sw[wv][i + 3];
        int s0 = ss[wv][i], s1 = ss[wv][i + 1], s2 = ss[wv][i + 2], s3 = ss[wv][i + 3];
        uint_t u0 = *(const uint_t*)(Hb + (size_t)s0 * 128 + lane * 2);
        uint_t u1 = *(const uint_t*)(Hb + (size_t)s1 * 128 + lane * 2);
        uint_t u2 = *(const uint_t*)(Hb + (size_t)s2 * 128 + lane * 2);
        uint_t u3 = *(const uint_t*)(Hb + (size_t)s3 * 128 + lane * 2);
        ax += w0 * __uint_as_float(u0 << 16) + w1 * __uint_as_float(u1 << 16)
            + w2 * __uint_as_float(u2 << 16) + w3 * __uint_as_float(u3 << 16);
        ay += w0 * __uint_as_float(u0 & 0xffff0000u) + w1 * __uint_as_float(u1 & 0xffff0000u)
            + w2 * __uint_as_float(u2 & 0xffff0000u) + w3 * __uint_as_float(u3 & 0xffff0000u);
    }
    for (; i < nl; ++i) {
        float w0 = sw[wv][i];
        int s0 = ss[wv][i];
        uint_t u0 = *(const uint_t*)(Hb + (size_t)s0 * 128 + lane * 2);
        ax += w0 * __uint_as_float(u0 << 16);
        ay += w0 * __uint_as_float(u0 & 0xffff0000u);
    }
    for (int j = CAP; j < deg; ++j) {   // correctness fallback, ~never taken
        int s0 = srcs[beg + j];
        float v = as_[s0] + adv; v = (v >= 0.f) ? v : 0.2f * v;
        float w0 = __expf(v - m);
        uint_t u0 = *(const uint_t*)(Hb + (size_t)s0 * 128 + lane * 2);
        ax += w0 * __uint_as_float(u0 << 16);
        ay += w0 * __uint_as_float(u0 & 0xffff0000u);
    }
    float2 o;
    o.x = fmaxf(ax * invd + b[lane * 2], 0.f);
    o.y = fmaxf(ay * invd + b[lane * 2 + 1], 0.f);
    *(float2*)(out + (size_t)wid * 128 + lane * 2) = o;
}

// ---- layer 2: fused softmax + aggregate (F=16, 4 slots/wave) + bias + lsm ----
__global__ void gat_fused16_lsm(const int* __restrict__ rowptr, const ushort_t* __restrict__ srcs,
                                const float* __restrict__ as_, const float* __restrict__ ad_,
                                const float* __restrict__ H, const float* __restrict__ b,
                                float* __restrict__ out) {
    __shared__ float sw[4][CAP];
    __shared__ int   ss[4][CAP];
    int wid = (blockIdx.x * blockDim.x + threadIdx.x) >> 6;
    int lane = threadIdx.x & 63;
    int wv = (threadIdx.x >> 6) & 3;
    int slot = lane >> 4, k = lane & 15;
    if (wid >= NODES) return;
    const int beg = rowptr[wid], deg = rowptr[wid + 1] - beg;
    const float adv = ad_[wid];
    float m = NEGF;
    for (int i = lane; i < deg; i += 64) {
        int s = srcs[beg + i];
        float v = as_[s] + adv;
        v = (v >= 0.f) ? v : 0.2f * v;
        if (i < CAP) { sw[wv][i] = v; ss[wv][i] = s; }
        m = fmaxf(m, v);
    }
    #pragma unroll
    for (int off = 32; off; off >>= 1) m = fmaxf(m, __shfl_xor(m, off));
    float den = 0.f;
    for (int i = lane; i < deg; i += 64) {
        float v;
        if (i < CAP) v = sw[wv][i];
        else { int s = srcs[beg + i]; v = as_[s] + adv; v = (v >= 0.f) ? v : 0.2f * v; }
        float w = __expf(v - m);
        if (i < CAP) sw[wv][i] = w;
        den += w;
    }
    #pragma unroll
    for (int off = 32; off; off >>= 1) den += __shfl_xor(den, off);
    const float invd = 1.f / (den + 1e-16f);
    float acc = 0.f;
    const int nl = deg < CAP ? deg : CAP;
    for (int i = slot; i < nl; i += 4) {
        acc += sw[wv][i] * H[(size_t)ss[wv][i] * 16 + k];
    }
    for (int j = CAP + slot; j < deg; j += 4) {   // fallback, ~never taken
        int s = srcs[beg + j];
        float v = as_[s] + adv; v = (v >= 0.f) ? v : 0.2f * v;
        acc += __expf(v - m) * H[(size_t)s * 16 + k];
    }
    acc += __shfl_xor(acc, 16);
    acc += __shfl_xor(acc, 32);
    float v = acc * invd + b[k];
    float mx = v;
    #pragma unroll
    for (int off = 1; off < 16; off <<= 1) mx = fmaxf(mx, __shfl_xor(mx, off));
    float ex = __expf(v - mx), ssum = ex;
    #pragma unroll
    for (int off = 1; off < 16; off <<= 1) ssum += __shfl_xor(ssum, off);
    float r = v - mx - __logf(ssum);
    if (lane < 16) out[(size_t)wid * 16 + k] = r;
}

extern "C" void kernel_launch(void* const* d_in, const int* in_sizes, int n_in,
                              void* d_out, int out_size, void* d_ws, size_t ws_size,
                              hipStream_t stream) {
    const float* x      = (const float*)d_in[0];
    const int*   ei     = (const int*)d_in[1];   // [2, E] int32 on device
    const float* W1     = (const float*)d_in[2];
    const float* a_src1 = (const float*)d_in[3];
    const float* a_dst1 = (const float*)d_in[4];
    const float* b1     = (const float*)d_in[5];
    const float* W2     = (const float*)d_in[6];
    const float* a_src2 = (const float*)d_in[7];
    const float* a_dst2 = (const float*)d_in[8];
    const float* b2     = (const float*)d_in[9];
    float* out = (float*)d_out;

    // ---- workspace layout ----
    float* p = (float*)d_ws;
    ushort_t* h1b = (ushort_t*)p; p += (size_t)NODES * 64;   // 12.8 MB as bf16
    float* agg1   = p; p += (size_t)NODES * 128;             // 25.6 MB
    float* h2     = p; p += (size_t)NODES * 16;              //  3.2 MB
    float* as_    = p; p += NODES;
    float* ad_    = p; p += NODES;
    int* ip = (int*)p;
    int* deg    = ip; ip += NODES;
    int* cursor = ip; ip += NODES;
    int* rowptr = ip; ip += NODES + 1;
    ushort_t* srcs = (ushort_t*)ip; ip += (ETOT + 1) / 2;
    int* bsum   = ip; ip += 256;

    const int EB = (ETOT + 255) / 256;
    const int NB = (NODES + 255) / 256;   // 196 chunks
    const int WAVEGRID = (NODES * 64 + 255) / 256;

    // ---- CSR build (shared by both layers) ----
    hipMemsetAsync(deg, 0, NODES * sizeof(int), stream);
    csr_hist<<<EB, 256, 0, stream>>>(ei, deg);
    scan1<<<NB, 256, 0, stream>>>(deg, bsum);
    scan2<<<1, 256, 0, stream>>>(bsum, NB);
    scan3<<<NB, 256, 0, stream>>>(deg, bsum, rowptr, cursor);
    csr_fill<<<EB, 256, 0, stream>>>(ei, cursor, srcs);

    // ---- layer 1 ----
    gemm_xw_alpha<<<(NODES + 31) / 32, 256, 0, stream>>>(x, W1, a_src1, a_dst1, h1b, as_, ad_, NODES);
    gat_fused128<<<WAVEGRID, 256, 0, stream>>>(rowptr, srcs, as_, ad_, h1b, b1, agg1);

    // ---- layer 2 ----
    gemm_hw2_alpha<<<(NODES * 16 + 255) / 256, 256, 0, stream>>>(agg1, W2, a_src2, a_dst2, h2, as_, ad_, NODES);
    gat_fused16_lsm<<<WAVEGRID, 256, 0, stream>>>(rowptr, srcs, as_, ad_, h2, b2, out);
}